// Round 10
// baseline (86.502 us; speedup 1.0000x reference)
//
#include <hip/hip_runtime.h>
#include <stdint.h>

typedef __bf16 bf16x8 __attribute__((ext_vector_type(8)));
typedef float f32x4 __attribute__((ext_vector_type(4)));
typedef unsigned short u16;
typedef const __attribute__((address_space(1))) void* as1_cvp;
typedef __attribute__((address_space(3))) void* as3_vp;

__device__ __forceinline__ u16 f2bf(float f) {
  union { float f; unsigned u; } v; v.f = f;
  unsigned r = v.u + 0x7fffu + ((v.u >> 16) & 1u);
  return (u16)(r >> 16);
}

// ---- single-block: histogram + stable counting-sort perm + tile map ----
// No atomics: per-thread counts -> wave-per-group shfl exclusive scan.
// tmap64: 64-row m-tiles for both GEMMs.
__global__ __launch_bounds__(256) void hist_perm_kernel(
    const int* __restrict__ idx, int n, int* __restrict__ starts,
    int* __restrict__ perm, int* __restrict__ tmap64) {
  __shared__ int cnt[4][256];
  __shared__ int gtot[4], gstart[4];
  const int t = threadIdx.x;
  const int rpt = (n + 255) >> 8;  // rows per thread (8 @ n=2048)
  const int base = t * rpt;
  int c[4] = {0, 0, 0, 0};
  for (int j = 0; j < rpt; ++j) {
    const int i = base + j;
    if (i < n) c[idx[i] & 3]++;
  }
  #pragma unroll
  for (int g = 0; g < 4; ++g) cnt[g][t] = c[g];
  __syncthreads();

  // wave w handles group w: 64 lanes, each covering 4 consecutive threads
  const int w = t >> 6, l = t & 63;
  {
    const int s0 = cnt[w][l * 4 + 0], s1 = cnt[w][l * 4 + 1];
    const int s2 = cnt[w][l * 4 + 2], s3 = cnt[w][l * 4 + 3];
    const int sum = s0 + s1 + s2 + s3;
    int sc = sum;  // inclusive scan over 64 lanes
    #pragma unroll
    for (int d = 1; d < 64; d <<= 1) {
      const int o = __shfl_up(sc, d, 64);
      if (l >= d) sc += o;
    }
    const int ex = sc - sum;  // exclusive
    cnt[w][l * 4 + 0] = ex;
    cnt[w][l * 4 + 1] = ex + s0;
    cnt[w][l * 4 + 2] = ex + s0 + s1;
    cnt[w][l * 4 + 3] = ex + s0 + s1 + s2;
    if (l == 63) gtot[w] = sc;
  }
  __syncthreads();

  if (t == 0) {
    int s = 0, nt64 = 0;
    for (int g = 0; g < 4; ++g) {
      gstart[g] = s;
      starts[g] = s;
      const int cg = gtot[g];
      for (int j = 0; j < cg; j += 64) tmap64[nt64++] = (g << 28) | (s + j);
      s += cg;
    }
    starts[4] = s;
    while (nt64 < 40) tmap64[nt64++] = -1;
  }
  __syncthreads();

  int run[4] = {0, 0, 0, 0};
  for (int j = 0; j < rpt; ++j) {
    const int i = base + j;
    if (i < n) {
      const int g = idx[i] & 3;
      perm[gstart[g] + cnt[g][t] + run[g]] = i;
      run[g]++;
    }
  }
}

// ---- fused prep: W transposes (blocks 0..4095) + x gather/convert (4096..6143) ----
// W [O][K][N] f32 -> WT [O][N][K] bf16 ; Xs[p] = bf16(x[perm[p]])
__global__ __launch_bounds__(256) void prep_kernel(
    const float* __restrict__ W1, u16* __restrict__ W1T,
    const float* __restrict__ W2, u16* __restrict__ W2T,
    const float* __restrict__ x, const int* __restrict__ perm,
    u16* __restrict__ Xs) {
  __shared__ float tile[64][65];
  int bid = blockIdx.x;
  if (bid >= 4096) {  // gather+convert: one row per block
    const int p = bid - 4096;
    const int b = perm[p];
    const float4 v = ((const float4*)(x + (size_t)b * 1024))[threadIdx.x];
    ushort4 u;
    u.x = f2bf(v.x); u.y = f2bf(v.y); u.z = f2bf(v.z); u.w = f2bf(v.w);
    ((ushort4*)(Xs + (size_t)p * 1024))[threadIdx.x] = u;
    return;
  }
  const float* W; u16* WT; int K, N, tx, ty, o;
  if (bid < 2048) {         // W1: K=1024, N=2048 -> 32x16x4 tiles
    W = W1; WT = W1T; K = 1024; N = 2048;
    o = bid >> 9; const int t = bid & 511; tx = t & 31; ty = t >> 5;
  } else {                  // W2: K=2048, N=1024 -> 16x32x4 tiles
    bid -= 2048;
    W = W2; WT = W2T; K = 2048; N = 1024;
    o = bid >> 9; const int t = bid & 511; tx = t & 15; ty = t >> 4;
  }
  const float* Wo = W + (size_t)o * K * N;
  u16* WTo = WT + (size_t)o * N * K;
  const int k0 = ty * 64, n0 = tx * 64;
  const int rr = threadIdx.x >> 4, cc = threadIdx.x & 15;
  #pragma unroll
  for (int j = 0; j < 4; ++j) {
    const int r = j * 16 + rr;
    const float4 v = *(const float4*)(Wo + (size_t)(k0 + r) * N + n0 + cc * 4);
    tile[r][cc * 4 + 0] = v.x; tile[r][cc * 4 + 1] = v.y;
    tile[r][cc * 4 + 2] = v.z; tile[r][cc * 4 + 3] = v.w;
  }
  __syncthreads();
  #pragma unroll
  for (int j = 0; j < 4; ++j) {
    const int nrow = j * 16 + rr;
    ushort4 u;
    u.x = f2bf(tile[cc * 4 + 0][nrow]);
    u.y = f2bf(tile[cc * 4 + 1][nrow]);
    u.z = f2bf(tile[cc * 4 + 2][nrow]);
    u.w = f2bf(tile[cc * 4 + 3][nrow]);
    *(ushort4*)(WTo + (size_t)(n0 + nrow) * K + k0 + cc * 4) = u;
  }
}

// ---- grouped GEMM: C[M,N] = A_sorted[M,K] @ WT[o][N,K]^T + bias ----
// Tile 64x128, BK=64, TWO waves; each wave owns full 64 x (wave's 64 cols):
// 4x4 frags x2 kk = 32 MFMA + 16 ds_read_b128 per wave per K-step (fat),
// while blocks stay small (48KB LDS -> 3 blocks/CU, wide grid).
// dbuf LDS, counted vmcnt(12), T2 XOR swizzle, T5 setprio, XCD swizzle.
// EPI 0: out bf16 (sorted order). EPI 1: out f32 scattered via perm.
template <int EPI, int NT_PAD, int KT, int NN, int NTN>
__global__ __launch_bounds__(128, 2) void gemm_kernel(
    const u16* __restrict__ A, const u16* __restrict__ BT,
    const float* __restrict__ bias, const int* __restrict__ starts,
    const int* __restrict__ tmap, const int* __restrict__ perm,
    u16* __restrict__ outH, float* __restrict__ outF) {
  constexpr int ABUF = 8192;           // A: 64 rows x 128B
  constexpr int BSTR = ABUF + 16384;   // + B: 128 rows x 128B
  __shared__ char smem[2 * BSTR];

  const int nwg = NT_PAD * NTN;        // % 8 == 0
  const int q = nwg >> 3;
  const int bid = blockIdx.x;
  const int swz = (bid & 7) * q + (bid >> 3);  // XCD-chunked bijective
  const int tile = swz % NT_PAD;               // m-tile fastest: B-panel L2 reuse
  const int n_t = swz / NT_PAD;

  const int tm = tmap[tile];
  if (tm < 0) return;
  const int o = tm >> 28;
  const int m_start = tm & 0x0FFFFFFF;
  const int g1 = starts[o + 1];
  const int n_start = n_t * 128;
  const u16* Bo = BT + (size_t)o * NN * KT;

  const int tid = threadIdx.x;
  const int w = tid >> 6;  // wave 0..1
  const int l = tid & 63;
  const int l8 = l & 7, ld8 = l >> 3;

  // T2: global source column pre-swizzled so linear LDS dest holds
  // LDS[row][unit] = global[row][unit ^ (row&7)]  (16B units, 8 per 128B row)
  const int src_unit = l8 ^ ld8;

  // A: 8 KB = 8 x 1KB loads, wave w does j=0..3 covering rows (w*4+j)*8+ld8
  const u16* pA[4];
  #pragma unroll
  for (int j = 0; j < 4; ++j) {
    int r = m_start + (w * 4 + j) * 8 + ld8;
    if (r >= g1) r = g1 - 1;  // clamp (stores predicated at epilogue)
    pA[j] = A + (size_t)r * KT + src_unit * 8;
  }
  // B: 16 KB = 16 x 1KB loads, wave w does j=0..7 covering rows (w*8+j)*8+ld8
  const u16* pB[8];
  #pragma unroll
  for (int j = 0; j < 8; ++j) {
    const int nr = n_start + (w * 8 + j) * 8 + ld8;
    pB[j] = Bo + (size_t)nr * KT + src_unit * 8;
  }

#define STAGE(dst_off)                                                         \
  {                                                                            \
    _Pragma("unroll")                                                          \
    for (int j = 0; j < 4; ++j)                                                \
      __builtin_amdgcn_global_load_lds((as1_cvp)pA[j],                         \
          (as3_vp)(smem + (dst_off) + (w * 4 + j) * 1024), 16, 0, 0);          \
    _Pragma("unroll")                                                          \
    for (int j = 0; j < 8; ++j)                                                \
      __builtin_amdgcn_global_load_lds((as1_cvp)pB[j],                         \
          (as3_vp)(smem + (dst_off) + ABUF + (w * 8 + j) * 1024), 16, 0, 0);   \
    _Pragma("unroll") for (int j = 0; j < 4; ++j) pA[j] += 64;                 \
    _Pragma("unroll") for (int j = 0; j < 8; ++j) pB[j] += 64;                 \
  }

  // fragment read byte offsets, T2 read-side XOR (row&7 == l&7 for frag rows)
  const int lrow = l & 15;
  const int lx = l & 7;
  const int lu = l >> 4;
  int offA[4][2], offB[4][2];
  #pragma unroll
  for (int a = 0; a < 4; ++a)
    #pragma unroll
    for (int kk = 0; kk < 2; ++kk)
      offA[a][kk] = (a * 16 + lrow) * 128 + (((kk * 4 + lu) ^ lx) << 4);
  #pragma unroll
  for (int b = 0; b < 4; ++b)
    #pragma unroll
    for (int kk = 0; kk < 2; ++kk)
      offB[b][kk] = (w * 64 + b * 16 + lrow) * 128 + (((kk * 4 + lu) ^ lx) << 4);

  f32x4 acc[4][4] = {};

  const int nK = KT >> 6;
  STAGE(0);  // prologue: tile 0 -> buf0
  for (int kt = 0; kt < nK; ++kt) {
    const int cur = (kt & 1) * BSTR;
    if (kt + 1 < nK) {
      STAGE(BSTR - cur);  // next tile -> other buffer (stays in flight)
      asm volatile("s_waitcnt vmcnt(12)" ::: "memory");  // prev stage landed
    } else {
      asm volatile("s_waitcnt vmcnt(0)" ::: "memory");
    }
    __builtin_amdgcn_s_barrier();  // buf[cur] valid for all waves

    bf16x8 af[4][2], bfr[4][2];
    #pragma unroll
    for (int a = 0; a < 4; ++a)
      #pragma unroll
      for (int kk = 0; kk < 2; ++kk)
        af[a][kk] = *(const bf16x8*)(smem + cur + offA[a][kk]);
    #pragma unroll
    for (int b = 0; b < 4; ++b)
      #pragma unroll
      for (int kk = 0; kk < 2; ++kk)
        bfr[b][kk] = *(const bf16x8*)(smem + cur + ABUF + offB[b][kk]);
    asm volatile("s_waitcnt lgkmcnt(0)" ::: "memory");  // my reads done
    __builtin_amdgcn_s_barrier();  // all reads done -> next STAGE may overwrite

    __builtin_amdgcn_s_setprio(1);
    #pragma unroll
    for (int kk = 0; kk < 2; ++kk)
      #pragma unroll
      for (int a = 0; a < 4; ++a)
        #pragma unroll
        for (int b = 0; b < 4; ++b)
          acc[a][b] = __builtin_amdgcn_mfma_f32_16x16x32_bf16(af[a][kk], bfr[b][kk], acc[a][b], 0, 0, 0);
    __builtin_amdgcn_s_setprio(0);
  }
#undef STAGE

  // epilogue: C/D layout col = l&15, row = (l>>4)*4 + r  [m89-verified]
  const int col_l = l & 15;
  const int row_l = (l >> 4) << 2;
  #pragma unroll
  for (int a = 0; a < 4; ++a) {
    #pragma unroll
    for (int b = 0; b < 4; ++b) {
      const int n = n_start + w * 64 + b * 16 + col_l;
      const float bv = bias[n];
      #pragma unroll
      for (int r = 0; r < 4; ++r) {
        const int p = m_start + a * 16 + row_l + r;
        if (p < g1) {
          if (EPI == 0) {
            outH[(size_t)p * NN + n] = f2bf(acc[a][b][r] + bv);
          } else {
            outF[(size_t)perm[p] * NN + n] = acc[a][b][r] + bv;
          }
        }
      }
    }
  }
}

extern "C" void kernel_launch(void* const* d_in, const int* in_sizes, int n_in,
                              void* d_out, int out_size, void* d_ws, size_t ws_size,
                              hipStream_t stream) {
  (void)n_in; (void)out_size; (void)ws_size;
  const float* x   = (const float*)d_in[0];
  const int*   idx = (const int*)d_in[1];
  const float* W1  = (const float*)d_in[2];
  const float* b1  = (const float*)d_in[3];
  const float* W2  = (const float*)d_in[4];
  const float* b2  = (const float*)d_in[5];
  float* out = (float*)d_out;

  const int B = in_sizes[1];  // 2048

  // workspace layout (~44.06 MB)
  char* ws = (char*)d_ws;
  u16* W1T     = (u16*)(ws);                    // 16 MB [o][N=2048][K=1024]
  u16* W2T     = (u16*)(ws + 16777216);         // 16 MB [o][N=1024][K=2048]
  u16* Xs      = (u16*)(ws + 33554432);         // B*1024 bf16 = 4 MB (sorted)
  u16* Hs      = (u16*)(ws + 37748736);         // B*2048 bf16 = 8 MB (sorted)
  int* perm    = (int*)(ws + 46137344);         // B ints
  int* starts  = (int*)(ws + 46137344 + 8192);  // 5 ints
  int* tmap64  = starts + 64;                   // 40 ints (live 64-row m-tiles)

  hist_perm_kernel<<<1, 256, 0, stream>>>(idx, B, starts, perm, tmap64);
  prep_kernel<<<4096 + B, 256, 0, stream>>>(W1, W1T, W2, W2T, x, perm, Xs);

  // GEMM1: N=2048, K=1024. 40 m x 16 n = 640 blocks, 128 thr (2 fat waves).
  gemm_kernel<0, 40, 1024, 2048, 16><<<640, 128, 0, stream>>>(
      Xs, W1T, b1, starts, tmap64, perm, Hs, nullptr);
  // GEMM2: N=1024, K=2048. 40 m x 8 n = 320 blocks, epilogue scatter via perm.
  gemm_kernel<1, 40, 2048, 1024, 8><<<320, 128, 0, stream>>>(
      Hs, W2T, b2, starts, tmap64, perm, nullptr, out);
}

// Round 11
// 78.640 us; speedup vs baseline: 1.1000x; 1.1000x over previous
//
#include <hip/hip_runtime.h>
#include <stdint.h>

typedef __bf16 bf16x8 __attribute__((ext_vector_type(8)));
typedef float f32x4 __attribute__((ext_vector_type(4)));
typedef unsigned short u16;
typedef const __attribute__((address_space(1))) void* as1_cvp;
typedef __attribute__((address_space(3))) void* as3_vp;

__device__ __forceinline__ u16 f2bf(float f) {
  union { float f; unsigned u; } v; v.f = f;
  unsigned r = v.u + 0x7fffu + ((v.u >> 16) & 1u);
  return (u16)(r >> 16);
}

// ---- single-block: histogram + stable counting-sort perm + tile maps ----
// No atomics: per-thread counts -> wave-per-group shfl exclusive scan.
// tmap128: 128-row m-tiles (GEMM1), tmap64: 64-row m-tiles (GEMM2).
__global__ __launch_bounds__(256) void hist_perm_kernel(
    const int* __restrict__ idx, int n, int* __restrict__ starts,
    int* __restrict__ perm, int* __restrict__ tmap128,
    int* __restrict__ tmap64) {
  __shared__ int cnt[4][256];
  __shared__ int gtot[4], gstart[4];
  const int t = threadIdx.x;
  const int rpt = (n + 255) >> 8;  // rows per thread (8 @ n=2048)
  const int base = t * rpt;
  int c[4] = {0, 0, 0, 0};
  for (int j = 0; j < rpt; ++j) {
    const int i = base + j;
    if (i < n) c[idx[i] & 3]++;
  }
  #pragma unroll
  for (int g = 0; g < 4; ++g) cnt[g][t] = c[g];
  __syncthreads();

  // wave w handles group w: 64 lanes, each covering 4 consecutive threads
  const int w = t >> 6, l = t & 63;
  {
    const int s0 = cnt[w][l * 4 + 0], s1 = cnt[w][l * 4 + 1];
    const int s2 = cnt[w][l * 4 + 2], s3 = cnt[w][l * 4 + 3];
    const int sum = s0 + s1 + s2 + s3;
    int sc = sum;  // inclusive scan over 64 lanes
    #pragma unroll
    for (int d = 1; d < 64; d <<= 1) {
      const int o = __shfl_up(sc, d, 64);
      if (l >= d) sc += o;
    }
    const int ex = sc - sum;  // exclusive
    cnt[w][l * 4 + 0] = ex;
    cnt[w][l * 4 + 1] = ex + s0;
    cnt[w][l * 4 + 2] = ex + s0 + s1;
    cnt[w][l * 4 + 3] = ex + s0 + s1 + s2;
    if (l == 63) gtot[w] = sc;
  }
  __syncthreads();

  if (t == 0) {
    int s = 0, nt128 = 0, nt64 = 0;
    for (int g = 0; g < 4; ++g) {
      gstart[g] = s;
      starts[g] = s;
      const int cg = gtot[g];
      for (int j = 0; j < cg; j += 128) tmap128[nt128++] = (g << 28) | (s + j);
      for (int j = 0; j < cg; j += 64)  tmap64[nt64++]  = (g << 28) | (s + j);
      s += cg;
    }
    starts[4] = s;
    while (nt128 < 20) tmap128[nt128++] = -1;
    while (nt64 < 40)  tmap64[nt64++]  = -1;
  }
  __syncthreads();

  int run[4] = {0, 0, 0, 0};
  for (int j = 0; j < rpt; ++j) {
    const int i = base + j;
    if (i < n) {
      const int g = idx[i] & 3;
      perm[gstart[g] + cnt[g][t] + run[g]] = i;
      run[g]++;
    }
  }
}

// ---- fused prep: W transposes (blocks 0..4095) + x gather/convert (4096..6143) ----
// W [O][K][N] f32 -> WT [O][N][K] bf16 ; Xs[p] = bf16(x[perm[p]])
// XCD-AFFINE remap: the block writing a WT n-panel runs on the XCD (bid&7)
// that the GEMM swizzle will later READ that panel from -> B-stages hit L2.
//   GEMM1 (NTN=16, chunks of 40 swz): XCD x reads n_t in {2x,2x+1} -> W1 tile
//   tx (64-col) has n_t = tx>>1, so xcd = tx>>2.
//   GEMM2 (NTN=8): XCD x reads n_t = x -> W2 tile tx has xcd = tx>>1.
__global__ __launch_bounds__(256) void prep_kernel(
    const float* __restrict__ W1, u16* __restrict__ W1T,
    const float* __restrict__ W2, u16* __restrict__ W2T,
    const float* __restrict__ x, const int* __restrict__ perm,
    u16* __restrict__ Xs) {
  __shared__ float tile[64][65];
  int bid = blockIdx.x;
  if (bid >= 4096) {  // gather+convert: one row per block
    const int p = bid - 4096;
    const int b = perm[p];
    const float4 v = ((const float4*)(x + (size_t)b * 1024))[threadIdx.x];
    ushort4 u;
    u.x = f2bf(v.x); u.y = f2bf(v.y); u.z = f2bf(v.z); u.w = f2bf(v.w);
    ((ushort4*)(Xs + (size_t)p * 1024))[threadIdx.x] = u;
    return;
  }
  const float* W; u16* WT; int K, N, tx, ty, o;
  if (bid < 2048) {         // W1: K=1024, N=2048 -> tx[0,32) x ty[0,16) x o[0,4)
    W = W1; WT = W1T; K = 1024; N = 2048;
    const int xcd = bid & 7, i = bid >> 3;        // i in [0,256)
    tx = (xcd << 2) | (i & 3);                    // xcd = tx>>2  (consumer match)
    ty = (i >> 2) & 15;
    o = i >> 6;
  } else {                  // W2: K=2048, N=1024 -> tx[0,16) x ty[0,32) x o[0,4)
    const int b = bid - 2048;                     // 2048%8==0 so XCD(bid)=b&7
    W = W2; WT = W2T; K = 2048; N = 1024;
    const int xcd = b & 7, i = b >> 3;            // i in [0,256)
    tx = (xcd << 1) | (i & 1);                    // xcd = tx>>1  (consumer match)
    ty = (i >> 1) & 31;
    o = i >> 6;
  }
  const float* Wo = W + (size_t)o * K * N;
  u16* WTo = WT + (size_t)o * N * K;
  const int k0 = ty * 64, n0 = tx * 64;
  const int rr = threadIdx.x >> 4, cc = threadIdx.x & 15;
  #pragma unroll
  for (int j = 0; j < 4; ++j) {
    const int r = j * 16 + rr;
    const float4 v = *(const float4*)(Wo + (size_t)(k0 + r) * N + n0 + cc * 4);
    tile[r][cc * 4 + 0] = v.x; tile[r][cc * 4 + 1] = v.y;
    tile[r][cc * 4 + 2] = v.z; tile[r][cc * 4 + 3] = v.w;
  }
  __syncthreads();
  #pragma unroll
  for (int j = 0; j < 4; ++j) {
    const int nrow = j * 16 + rr;
    ushort4 u;
    u.x = f2bf(tile[cc * 4 + 0][nrow]);
    u.y = f2bf(tile[cc * 4 + 1][nrow]);
    u.z = f2bf(tile[cc * 4 + 2][nrow]);
    u.w = f2bf(tile[cc * 4 + 3][nrow]);
    *(ushort4*)(WTo + (size_t)(n0 + nrow) * K + k0 + cc * 4) = u;
  }
}

// ---- grouped GEMM: C[M,N] = A_sorted[M,K] @ WT[o][N,K]^T + bias ----
// Tile TM x 128, BK=64, 4 waves (2x2), wave (TM/2)x64. Compact tmap grid.
// dbuf LDS, counted vmcnt, T2 XOR swizzle, T5 setprio, XCD-chunked swizzle.
// EPI 0: out bf16 (sorted order). EPI 1: out f32 scattered via perm.
template <int EPI, int TM, int NT_PAD, int KT, int NN, int NTN>
__global__ __launch_bounds__(256, 2) void gemm_kernel(
    const u16* __restrict__ A, const u16* __restrict__ BT,
    const float* __restrict__ bias, const int* __restrict__ starts,
    const int* __restrict__ tmap, const int* __restrict__ perm,
    u16* __restrict__ outH, float* __restrict__ outF) {
  constexpr int MR = TM / 32;          // A-loads & m-frags per wave
  constexpr int ABUF = TM * 128;       // A bytes per buffer
  constexpr int BSTR = ABUF + 16384;   // buffer stride (A + B)
  __shared__ char smem[2 * BSTR];

  const int nwg = NT_PAD * NTN;        // % 8 == 0
  const int q = nwg >> 3;
  const int bid = blockIdx.x;
  const int swz = (bid & 7) * q + (bid >> 3);  // XCD-chunked bijective
  const int tile = swz % NT_PAD;               // m-tile fastest: B-panel L2 reuse
  const int n_t = swz / NT_PAD;

  const int tm = tmap[tile];
  if (tm < 0) return;
  const int o = tm >> 28;
  const int m_start = tm & 0x0FFFFFFF;
  const int g1 = starts[o + 1];
  const int n_start = n_t * 128;
  const u16* Bo = BT + (size_t)o * NN * KT;

  const int tid = threadIdx.x;
  const int w = tid >> 6;  // wave 0..3
  const int l = tid & 63;
  const int wm = w >> 1, wn = w & 1;
  const int l8 = l & 7, ld8 = l >> 3;

  // T2: global source column pre-swizzled so linear LDS dest holds
  // LDS[row][unit] = global[row][unit ^ (row&7)]  (16B units, 8 per 128B row)
  const int src_unit = l8 ^ (ld8 & 7);

  const u16* pA[MR];
  #pragma unroll
  for (int j = 0; j < MR; ++j) {
    int r = m_start + (j * 4 + w) * 8 + ld8;
    if (r >= g1) r = g1 - 1;  // clamp (stores predicated at epilogue)
    pA[j] = A + (size_t)r * KT + src_unit * 8;
  }
  const u16* pB[4];
  #pragma unroll
  for (int j = 0; j < 4; ++j) {
    const int nr = n_start + (j * 4 + w) * 8 + ld8;
    pB[j] = Bo + (size_t)nr * KT + src_unit * 8;
  }

#define STAGE(dst_off)                                                         \
  {                                                                            \
    _Pragma("unroll")                                                          \
    for (int j = 0; j < MR; ++j)                                               \
      __builtin_amdgcn_global_load_lds((as1_cvp)pA[j],                         \
          (as3_vp)(smem + (dst_off) + (j * 4 + w) * 1024), 16, 0, 0);          \
    _Pragma("unroll")                                                          \
    for (int j = 0; j < 4; ++j)                                                \
      __builtin_amdgcn_global_load_lds((as1_cvp)pB[j],                         \
          (as3_vp)(smem + (dst_off) + ABUF + (j * 4 + w) * 1024), 16, 0, 0);   \
    _Pragma("unroll") for (int j = 0; j < MR; ++j) pA[j] += 64;                \
    _Pragma("unroll") for (int j = 0; j < 4; ++j) pB[j] += 64;                 \
  }

  // fragment read byte offsets, T2 read-side XOR (row&7 == l&7 for frag rows)
  const int lrow = l & 15;
  const int lx = l & 7;
  const int lu = l >> 4;
  int offA[MR][2], offB[4][2];
  #pragma unroll
  for (int a = 0; a < MR; ++a)
    #pragma unroll
    for (int kk = 0; kk < 2; ++kk)
      offA[a][kk] = (wm * (TM / 2) + a * 16 + lrow) * 128 + (((kk * 4 + lu) ^ lx) << 4);
  #pragma unroll
  for (int b = 0; b < 4; ++b)
    #pragma unroll
    for (int kk = 0; kk < 2; ++kk)
      offB[b][kk] = (wn * 64 + b * 16 + lrow) * 128 + (((kk * 4 + lu) ^ lx) << 4);

  f32x4 acc[MR][4] = {};

  const int nK = KT >> 6;
  STAGE(0);  // prologue: tile 0 -> buf0
  for (int kt = 0; kt < nK; ++kt) {
    const int cur = (kt & 1) * BSTR;
    if (kt + 1 < nK) {
      STAGE(BSTR - cur);  // next tile -> other buffer (stays in flight)
      if constexpr (TM == 128)
        asm volatile("s_waitcnt vmcnt(8)" ::: "memory");  // prev stage landed
      else
        asm volatile("s_waitcnt vmcnt(6)" ::: "memory");
    } else {
      asm volatile("s_waitcnt vmcnt(0)" ::: "memory");
    }
    __builtin_amdgcn_s_barrier();  // buf[cur] valid for all waves

    bf16x8 af[MR][2], bfr[4][2];
    #pragma unroll
    for (int a = 0; a < MR; ++a)
      #pragma unroll
      for (int kk = 0; kk < 2; ++kk)
        af[a][kk] = *(const bf16x8*)(smem + cur + offA[a][kk]);
    #pragma unroll
    for (int b = 0; b < 4; ++b)
      #pragma unroll
      for (int kk = 0; kk < 2; ++kk)
        bfr[b][kk] = *(const bf16x8*)(smem + cur + ABUF + offB[b][kk]);
    asm volatile("s_waitcnt lgkmcnt(0)" ::: "memory");  // my reads done
    __builtin_amdgcn_s_barrier();  // all reads done -> next STAGE may overwrite

    __builtin_amdgcn_s_setprio(1);
    #pragma unroll
    for (int kk = 0; kk < 2; ++kk)
      #pragma unroll
      for (int a = 0; a < MR; ++a)
        #pragma unroll
        for (int b = 0; b < 4; ++b)
          acc[a][b] = __builtin_amdgcn_mfma_f32_16x16x32_bf16(af[a][kk], bfr[b][kk], acc[a][b], 0, 0, 0);
    __builtin_amdgcn_s_setprio(0);
  }
#undef STAGE

  // epilogue: C/D layout col = l&15, row = (l>>4)*4 + r  [m89-verified]
  const int col_l = l & 15;
  const int row_l = (l >> 4) << 2;
  #pragma unroll
  for (int a = 0; a < MR; ++a) {
    #pragma unroll
    for (int b = 0; b < 4; ++b) {
      const int n = n_start + wn * 64 + b * 16 + col_l;
      const float bv = bias[n];
      #pragma unroll
      for (int r = 0; r < 4; ++r) {
        const int p = m_start + wm * (TM / 2) + a * 16 + row_l + r;
        if (p < g1) {
          if (EPI == 0) {
            outH[(size_t)p * NN + n] = f2bf(acc[a][b][r] + bv);
          } else {
            outF[(size_t)perm[p] * NN + n] = acc[a][b][r] + bv;
          }
        }
      }
    }
  }
}

extern "C" void kernel_launch(void* const* d_in, const int* in_sizes, int n_in,
                              void* d_out, int out_size, void* d_ws, size_t ws_size,
                              hipStream_t stream) {
  (void)n_in; (void)out_size; (void)ws_size;
  const float* x   = (const float*)d_in[0];
  const int*   idx = (const int*)d_in[1];
  const float* W1  = (const float*)d_in[2];
  const float* b1  = (const float*)d_in[3];
  const float* W2  = (const float*)d_in[4];
  const float* b2  = (const float*)d_in[5];
  float* out = (float*)d_out;

  const int B = in_sizes[1];  // 2048

  // workspace layout (~44.06 MB)
  char* ws = (char*)d_ws;
  u16* W1T     = (u16*)(ws);                    // 16 MB [o][N=2048][K=1024]
  u16* W2T     = (u16*)(ws + 16777216);         // 16 MB [o][N=1024][K=2048]
  u16* Xs      = (u16*)(ws + 33554432);         // B*1024 bf16 = 4 MB (sorted)
  u16* Hs      = (u16*)(ws + 37748736);         // B*2048 bf16 = 8 MB (sorted)
  int* perm    = (int*)(ws + 46137344);         // B ints
  int* starts  = (int*)(ws + 46137344 + 8192);  // 5 ints
  int* tmap128 = starts + 64;                   // 20 ints
  int* tmap64  = starts + 128;                  // 40 ints

  hist_perm_kernel<<<1, 256, 0, stream>>>(idx, B, starts, perm, tmap128, tmap64);
  prep_kernel<<<4096 + B, 256, 0, stream>>>(W1, W1T, W2, W2T, x, perm, Xs);

  // GEMM1: TM=128, N=2048, K=1024. 20 x 16 = 320 blocks (~95% live).
  gemm_kernel<0, 128, 20, 1024, 2048, 16><<<320, 256, 0, stream>>>(
      Xs, W1T, b1, starts, tmap128, perm, Hs, nullptr);
  // GEMM2: TM=64, N=1024, K=2048. 40 x 8 = 320 blocks, epilogue scatter via perm.
  gemm_kernel<1, 64, 40, 2048, 1024, 8><<<320, 256, 0, stream>>>(
      Hs, W2T, b2, starts, tmap64, perm, nullptr, out);
}

// Round 12
// 72.727 us; speedup vs baseline: 1.1894x; 1.0813x over previous
//
#include <hip/hip_runtime.h>
#include <stdint.h>

typedef __bf16 bf16x8 __attribute__((ext_vector_type(8)));
typedef float f32x4 __attribute__((ext_vector_type(4)));
typedef unsigned short u16;
typedef const __attribute__((address_space(1))) void* as1_cvp;
typedef __attribute__((address_space(3))) void* as3_vp;

__device__ __forceinline__ u16 f2bf(float f) {
  union { float f; unsigned u; } v; v.f = f;
  unsigned r = v.u + 0x7fffu + ((v.u >> 16) & 1u);
  return (u16)(r >> 16);
}

// ---- single-block: histogram + stable counting-sort perm + tile maps ----
__global__ __launch_bounds__(256) void hist_perm_kernel(
    const int* __restrict__ idx, int n, int* __restrict__ starts,
    int* __restrict__ perm, int* __restrict__ tmap128,
    int* __restrict__ tmap64) {
  __shared__ int cnt[4][256];
  __shared__ int gtot[4], gstart[4];
  const int t = threadIdx.x;
  const int rpt = (n + 255) >> 8;
  const int base = t * rpt;
  int c[4] = {0, 0, 0, 0};
  for (int j = 0; j < rpt; ++j) {
    const int i = base + j;
    if (i < n) c[idx[i] & 3]++;
  }
  #pragma unroll
  for (int g = 0; g < 4; ++g) cnt[g][t] = c[g];
  __syncthreads();
  const int w = t >> 6, l = t & 63;
  {
    const int s0 = cnt[w][l * 4 + 0], s1 = cnt[w][l * 4 + 1];
    const int s2 = cnt[w][l * 4 + 2], s3 = cnt[w][l * 4 + 3];
    const int sum = s0 + s1 + s2 + s3;
    int sc = sum;
    #pragma unroll
    for (int d = 1; d < 64; d <<= 1) {
      const int o = __shfl_up(sc, d, 64);
      if (l >= d) sc += o;
    }
    const int ex = sc - sum;
    cnt[w][l * 4 + 0] = ex;
    cnt[w][l * 4 + 1] = ex + s0;
    cnt[w][l * 4 + 2] = ex + s0 + s1;
    cnt[w][l * 4 + 3] = ex + s0 + s1 + s2;
    if (l == 63) gtot[w] = sc;
  }
  __syncthreads();
  if (t == 0) {
    int s = 0, nt128 = 0, nt64 = 0;
    for (int g = 0; g < 4; ++g) {
      gstart[g] = s;
      starts[g] = s;
      const int cg = gtot[g];
      for (int j = 0; j < cg; j += 128) tmap128[nt128++] = (g << 28) | (s + j);
      for (int j = 0; j < cg; j += 64)  tmap64[nt64++]  = (g << 28) | (s + j);
      s += cg;
    }
    starts[4] = s;
    while (nt128 < 20) tmap128[nt128++] = -1;
    while (nt64 < 40)  tmap64[nt64++]  = -1;
  }
  __syncthreads();
  int run[4] = {0, 0, 0, 0};
  for (int j = 0; j < rpt; ++j) {
    const int i = base + j;
    if (i < n) {
      const int g = idx[i] & 3;
      perm[gstart[g] + cnt[g][t] + run[g]] = i;
      run[g]++;
    }
  }
}

// ---- shared transpose body: W [K][N] f32 tile -> WT [N][K] bf16 ----
__device__ __forceinline__ void wtrans_body(
    float (*tile)[65], const float* __restrict__ W, u16* __restrict__ WT,
    int K, int N, int tx, int ty, int o) {
  const float* Wo = W + (size_t)o * K * N;
  u16* WTo = WT + (size_t)o * N * K;
  const int k0 = ty * 64, n0 = tx * 64;
  const int rr = threadIdx.x >> 4, cc = threadIdx.x & 15;
  #pragma unroll
  for (int j = 0; j < 4; ++j) {
    const int r = j * 16 + rr;
    const float4 v = *(const float4*)(Wo + (size_t)(k0 + r) * N + n0 + cc * 4);
    tile[r][cc * 4 + 0] = v.x; tile[r][cc * 4 + 1] = v.y;
    tile[r][cc * 4 + 2] = v.z; tile[r][cc * 4 + 3] = v.w;
  }
  __syncthreads();
  #pragma unroll
  for (int j = 0; j < 4; ++j) {
    const int nrow = j * 16 + rr;
    ushort4 u;
    u.x = f2bf(tile[cc * 4 + 0][nrow]);
    u.y = f2bf(tile[cc * 4 + 1][nrow]);
    u.z = f2bf(tile[cc * 4 + 2][nrow]);
    u.w = f2bf(tile[cc * 4 + 3][nrow]);
    *(ushort4*)(WTo + (size_t)(n0 + nrow) * K + k0 + cc * 4) = u;
  }
}

// ---- k1: W1T transpose (blocks 0..2047) ∥ x gather/convert (2048..4095) ----
__global__ __launch_bounds__(256) void w1t_gather_kernel(
    const float* __restrict__ W1, u16* __restrict__ W1T,
    const float* __restrict__ x, const int* __restrict__ perm,
    u16* __restrict__ Xs) {
  __shared__ float tile[64][65];
  const int bid = blockIdx.x;
  if (bid >= 2048) {  // gather+convert one sorted row
    const int p = bid - 2048;
    const int b = perm[p];
    const float4 v = ((const float4*)(x + (size_t)b * 1024))[threadIdx.x];
    ushort4 u;
    u.x = f2bf(v.x); u.y = f2bf(v.y); u.z = f2bf(v.z); u.w = f2bf(v.w);
    ((ushort4*)(Xs + (size_t)p * 1024))[threadIdx.x] = u;
    return;
  }
  // W1: K=1024, N=2048; XCD-affine decode (consumer xcd = tx>>2)
  const int xcd = bid & 7, i = bid >> 3;
  const int tx = (xcd << 2) | (i & 3);
  const int ty = (i >> 2) & 15;
  const int o = i >> 6;
  wtrans_body(tile, W1, W1T, 1024, 2048, tx, ty, o);
}

// ---- grouped GEMM body: C[M,N] = A_sorted[M,K] @ WT[o][N,K]^T + bias ----
// Tile TM x 128, BK=64, 4 waves (2x2). dbuf LDS, counted vmcnt, T2, T5.
// EPI 0: out bf16 (sorted order). EPI 1: out f32 scattered via perm.
template <int EPI, int TM, int NT_PAD, int KT, int NN, int NTN>
__device__ __forceinline__ void gemm_body(
    char* smem, int bid,
    const u16* __restrict__ A, const u16* __restrict__ BT,
    const float* __restrict__ bias, const int* __restrict__ starts,
    const int* __restrict__ tmap, const int* __restrict__ perm,
    u16* __restrict__ outH, float* __restrict__ outF) {
  constexpr int MR = TM / 32;
  constexpr int ABUF = TM * 128;
  constexpr int BSTR = ABUF + 16384;

  const int nwg = NT_PAD * NTN;        // % 8 == 0
  const int q = nwg >> 3;
  const int swz = (bid & 7) * q + (bid >> 3);  // XCD-chunked bijective
  const int tile = swz % NT_PAD;
  const int n_t = swz / NT_PAD;

  const int tm = tmap[tile];
  if (tm < 0) return;
  const int o = tm >> 28;
  const int m_start = tm & 0x0FFFFFFF;
  const int g1 = starts[o + 1];
  const int n_start = n_t * 128;
  const u16* Bo = BT + (size_t)o * NN * KT;

  const int tid = threadIdx.x;
  const int w = tid >> 6;
  const int l = tid & 63;
  const int wm = w >> 1, wn = w & 1;
  const int l8 = l & 7, ld8 = l >> 3;

  // T2: pre-swizzled global source so linear LDS dest holds swizzled layout
  const int src_unit = l8 ^ (ld8 & 7);

  const u16* pA[MR];
  #pragma unroll
  for (int j = 0; j < MR; ++j) {
    int r = m_start + (j * 4 + w) * 8 + ld8;
    if (r >= g1) r = g1 - 1;
    pA[j] = A + (size_t)r * KT + src_unit * 8;
  }
  const u16* pB[4];
  #pragma unroll
  for (int j = 0; j < 4; ++j) {
    const int nr = n_start + (j * 4 + w) * 8 + ld8;
    pB[j] = Bo + (size_t)nr * KT + src_unit * 8;
  }

#define STAGE(dst_off)                                                         \
  {                                                                            \
    _Pragma("unroll")                                                          \
    for (int j = 0; j < MR; ++j)                                               \
      __builtin_amdgcn_global_load_lds((as1_cvp)pA[j],                         \
          (as3_vp)(smem + (dst_off) + (j * 4 + w) * 1024), 16, 0, 0);          \
    _Pragma("unroll")                                                          \
    for (int j = 0; j < 4; ++j)                                                \
      __builtin_amdgcn_global_load_lds((as1_cvp)pB[j],                         \
          (as3_vp)(smem + (dst_off) + ABUF + (j * 4 + w) * 1024), 16, 0, 0);   \
    _Pragma("unroll") for (int j = 0; j < MR; ++j) pA[j] += 64;                \
    _Pragma("unroll") for (int j = 0; j < 4; ++j) pB[j] += 64;                 \
  }

  const int lrow = l & 15;
  const int lx = l & 7;
  const int lu = l >> 4;
  int offA[MR][2], offB[4][2];
  #pragma unroll
  for (int a = 0; a < MR; ++a)
    #pragma unroll
    for (int kk = 0; kk < 2; ++kk)
      offA[a][kk] = (wm * (TM / 2) + a * 16 + lrow) * 128 + (((kk * 4 + lu) ^ lx) << 4);
  #pragma unroll
  for (int b = 0; b < 4; ++b)
    #pragma unroll
    for (int kk = 0; kk < 2; ++kk)
      offB[b][kk] = (wn * 64 + b * 16 + lrow) * 128 + (((kk * 4 + lu) ^ lx) << 4);

  f32x4 acc[MR][4] = {};

  const int nK = KT >> 6;
  STAGE(0);
  for (int kt = 0; kt < nK; ++kt) {
    const int cur = (kt & 1) * BSTR;
    if (kt + 1 < nK) {
      STAGE(BSTR - cur);
      if constexpr (TM == 128)
        asm volatile("s_waitcnt vmcnt(8)" ::: "memory");
      else
        asm volatile("s_waitcnt vmcnt(6)" ::: "memory");
    } else {
      asm volatile("s_waitcnt vmcnt(0)" ::: "memory");
    }
    __builtin_amdgcn_s_barrier();

    bf16x8 af[MR][2], bfr[4][2];
    #pragma unroll
    for (int a = 0; a < MR; ++a)
      #pragma unroll
      for (int kk = 0; kk < 2; ++kk)
        af[a][kk] = *(const bf16x8*)(smem + cur + offA[a][kk]);
    #pragma unroll
    for (int b = 0; b < 4; ++b)
      #pragma unroll
      for (int kk = 0; kk < 2; ++kk)
        bfr[b][kk] = *(const bf16x8*)(smem + cur + ABUF + offB[b][kk]);
    asm volatile("s_waitcnt lgkmcnt(0)" ::: "memory");
    __builtin_amdgcn_s_barrier();

    __builtin_amdgcn_s_setprio(1);
    #pragma unroll
    for (int kk = 0; kk < 2; ++kk)
      #pragma unroll
      for (int a = 0; a < MR; ++a)
        #pragma unroll
        for (int b = 0; b < 4; ++b)
          acc[a][b] = __builtin_amdgcn_mfma_f32_16x16x32_bf16(af[a][kk], bfr[b][kk], acc[a][b], 0, 0, 0);
    __builtin_amdgcn_s_setprio(0);
  }
#undef STAGE

  const int col_l = l & 15;
  const int row_l = (l >> 4) << 2;
  #pragma unroll
  for (int a = 0; a < MR; ++a) {
    #pragma unroll
    for (int b = 0; b < 4; ++b) {
      const int n = n_start + wn * 64 + b * 16 + col_l;
      const float bv = bias[n];
      #pragma unroll
      for (int r = 0; r < 4; ++r) {
        const int p = m_start + wm * (TM / 2) + a * 16 + row_l + r;
        if (p < g1) {
          if (EPI == 0) {
            outH[(size_t)p * NN + n] = f2bf(acc[a][b][r] + bv);
          } else {
            outF[(size_t)perm[p] * NN + n] = acc[a][b][r] + bv;
          }
        }
      }
    }
  }
}

// ---- k2: GEMM1 (blocks 0..319) ∥ W2T transpose (blocks 320..2367) ----
// GEMM1 needs only W1T/Xs; W2T is produced here for GEMM2 (next launch).
__global__ __launch_bounds__(256, 2) void gemm1_w2t_kernel(
    const u16* __restrict__ Xs, const u16* __restrict__ W1T,
    const float* __restrict__ b1, const int* __restrict__ starts,
    const int* __restrict__ tmap128, u16* __restrict__ Hs,
    const float* __restrict__ W2, u16* __restrict__ W2T) {
  __shared__ char smem[65536];
  const int bid = blockIdx.x;
  if (bid < 320) {
    gemm_body<0, 128, 20, 1024, 2048, 16>(
        smem, bid, Xs, W1T, b1, starts, tmap128, nullptr, Hs, nullptr);
  } else {
    // W2: K=2048, N=1024; XCD-affine decode (consumer xcd = tx>>1).
    // 320 % 8 == 0 so (bid-320)&7 preserves the bid&7 XCD parity.
    const int b = bid - 320;
    const int xcd = b & 7, i = b >> 3;
    const int tx = (xcd << 1) | (i & 1);
    const int ty = (i >> 1) & 31;
    const int o = i >> 6;
    wtrans_body((float(*)[65])smem, W2, W2T, 2048, 1024, tx, ty, o);
  }
}

// ---- k3: GEMM2 ----
__global__ __launch_bounds__(256, 2) void gemm2_kernel(
    const u16* __restrict__ Hs, const u16* __restrict__ W2T,
    const float* __restrict__ b2, const int* __restrict__ starts,
    const int* __restrict__ tmap64, const int* __restrict__ perm,
    float* __restrict__ out) {
  __shared__ char smem[49152];
  gemm_body<1, 64, 40, 2048, 1024, 8>(
      smem, blockIdx.x, Hs, W2T, b2, starts, tmap64, perm, nullptr, out);
}

extern "C" void kernel_launch(void* const* d_in, const int* in_sizes, int n_in,
                              void* d_out, int out_size, void* d_ws, size_t ws_size,
                              hipStream_t stream) {
  (void)n_in; (void)out_size; (void)ws_size;
  const float* x   = (const float*)d_in[0];
  const int*   idx = (const int*)d_in[1];
  const float* W1  = (const float*)d_in[2];
  const float* b1  = (const float*)d_in[3];
  const float* W2  = (const float*)d_in[4];
  const float* b2  = (const float*)d_in[5];
  float* out = (float*)d_out;

  const int B = in_sizes[1];  // 2048

  // workspace layout (~44.06 MB)
  char* ws = (char*)d_ws;
  u16* W1T     = (u16*)(ws);                    // 16 MB [o][N=2048][K=1024]
  u16* W2T     = (u16*)(ws + 16777216);         // 16 MB [o][N=1024][K=2048]
  u16* Xs      = (u16*)(ws + 33554432);         // B*1024 bf16 = 4 MB (sorted)
  u16* Hs      = (u16*)(ws + 37748736);         // B*2048 bf16 = 8 MB (sorted)
  int* perm    = (int*)(ws + 46137344);         // B ints
  int* starts  = (int*)(ws + 46137344 + 8192);  // 5 ints
  int* tmap128 = starts + 64;                   // 20 ints
  int* tmap64  = starts + 128;                  // 40 ints

  // k0: ranks/maps (3 µs, 1 block)
  hist_perm_kernel<<<1, 256, 0, stream>>>(idx, B, starts, perm, tmap128, tmap64);
  // k1: W1T transpose ∥ x gather (independent work, one grid)
  w1t_gather_kernel<<<2048 + B, 256, 0, stream>>>(W1, W1T, x, perm, Xs);
  // k2: GEMM1 ∥ W2T transpose (W2T streams through GEMM1's idle memory pipe)
  gemm1_w2t_kernel<<<320 + 2048, 256, 0, stream>>>(
      Xs, W1T, b1, starts, tmap128, Hs, W2, W2T);
  // k3: GEMM2 (epilogue: +b2, scatter via perm, f32)
  gemm2_kernel<<<320, 256, 0, stream>>>(Hs, W2T, b2, starts, tmap64, perm, out);
}